// Round 1
// baseline (3951.081 us; speedup 1.0000x reference)
//
#include <hip/hip_runtime.h>
#include <math.h>

// Problem constants
// B=1, S=512, N=384, D=64, H=32, DP=128, DQK=64
#define SS 512
#define NN 384
#define DD 64
#define HH 32
#define JC 48          // j's per chunk
#define NCHUNK 8       // 384/48
#define NCCOLS 1536    // JC*32

// ws layout (float offsets)
#define WS_X        0u          // [512*384][64]           = 12582912
#define WS_A        12582912u   // [12288][512]            =  6291456
#define WS_B        18874368u   // [12288][512]            =  6291456
#define WS_QN       25165824u   // [2][384][64]            =    49152
#define WS_SW       25214976u   // [2][512]                =     1024
#define WS_WSQ      25216000u   // [512]                   =      512
#define WS_SCRATCH  25216512u   // kraw [196608][128] then outer [12288][1536] = 25165824

// ---------------- K1: LayerNorm over D=64, one wave per row ----------------
__global__ __launch_bounds__(256) void k1_ln(const float* __restrict__ msa,
                                             const float* __restrict__ g,
                                             const float* __restrict__ bb,
                                             float* __restrict__ x) {
    int row  = blockIdx.x * 4 + (threadIdx.x >> 6);
    int lane = threadIdx.x & 63;
    float v = msa[(size_t)row * 64 + lane];
    float sum = v;
    #pragma unroll
    for (int m = 1; m < 64; m <<= 1) sum += __shfl_xor(sum, m);
    float mean = sum * (1.0f / 64.0f);
    float dv = v - mean;
    float sq = dv * dv;
    #pragma unroll
    for (int m = 1; m < 64; m <<= 1) sq += __shfl_xor(sq, m);
    float r = rsqrtf(sq * (1.0f / 64.0f) + 1e-5f);
    x[(size_t)row * 64 + lane] = dv * r * g[lane] + bb[lane];
}

// ---------------- K2: q projection (s=0 rows) + LN ----------------
__global__ __launch_bounds__(128) void k2_q(const float* __restrict__ x,
                                            const float* __restrict__ Wq,
                                            const float* __restrict__ qg,
                                            const float* __restrict__ qb,
                                            float* __restrict__ qn) {
    int n = blockIdx.x;
    int t = threadIdx.x >> 6;   // 0,1
    int d = threadIdx.x & 63;
    const float* xr = x + (size_t)n * 64;           // row (s=0, n)
    const float* w  = Wq + (size_t)(t * 64 + d) * 64;
    float acc = 0.f;
    #pragma unroll 8
    for (int dd = 0; dd < 64; ++dd) acc += xr[dd] * w[dd];
    float sum = acc;
    #pragma unroll
    for (int m = 1; m < 64; m <<= 1) sum += __shfl_xor(sum, m);
    float mean = sum * (1.0f / 64.0f);
    float dv = acc - mean;
    float sq = dv * dv;
    #pragma unroll
    for (int m = 1; m < 64; m <<= 1) sq += __shfl_xor(sq, m);
    float r = rsqrtf(sq * (1.0f / 64.0f) + 1e-5f);
    qn[(size_t)(t * 384 + n) * 64 + d] = dv * r * qg[d] + qb[d];
}

// ---------------- Generic NT GEMM: C[M][N] = A[M][K] @ B[N][K]^T ----------------
// tiles 128x128, 256 threads, thread 8x8, K chunks of 32, transposed LDS staging.
__global__ __launch_bounds__(256) void gemm_nt(const float* __restrict__ A,
                                               const float* __restrict__ Bm,
                                               float* __restrict__ C,
                                               int K, int lda, int ldb, int ldc) {
    __shared__ float AsT[32][132];
    __shared__ float BsT[32][132];
    int t  = threadIdx.x;
    int m0 = blockIdx.x * 128, n0 = blockIdx.y * 128;
    int tr = t >> 4, tc = t & 15;
    float acc[8][8] = {};
    int rrow = t >> 3;           // 0..31
    int kk   = (t & 7) * 4;
    for (int k0 = 0; k0 < K; k0 += 32) {
        #pragma unroll
        for (int l = 0; l < 4; ++l) {
            int row = rrow + 32 * l;
            float4 va = *(const float4*)(A + (size_t)(m0 + row) * lda + k0 + kk);
            AsT[kk + 0][row] = va.x; AsT[kk + 1][row] = va.y;
            AsT[kk + 2][row] = va.z; AsT[kk + 3][row] = va.w;
            float4 vb = *(const float4*)(Bm + (size_t)(n0 + row) * ldb + k0 + kk);
            BsT[kk + 0][row] = vb.x; BsT[kk + 1][row] = vb.y;
            BsT[kk + 2][row] = vb.z; BsT[kk + 3][row] = vb.w;
        }
        __syncthreads();
        #pragma unroll 4
        for (int k = 0; k < 32; ++k) {
            float a[8], b[8];
            *(float4*)&a[0] = *(const float4*)&AsT[k][tr * 8];
            *(float4*)&a[4] = *(const float4*)&AsT[k][tr * 8 + 4];
            *(float4*)&b[0] = *(const float4*)&BsT[k][tc * 8];
            *(float4*)&b[4] = *(const float4*)&BsT[k][tc * 8 + 4];
            #pragma unroll
            for (int q = 0; q < 8; ++q)
                #pragma unroll
                for (int j = 0; j < 8; ++j)
                    acc[q][j] += a[q] * b[j];
        }
        __syncthreads();
    }
    #pragma unroll
    for (int q = 0; q < 8; ++q) {
        float* cp = C + (size_t)(m0 + tr * 8 + q) * ldc + n0 + tc * 8;
        *(float4*)cp       = make_float4(acc[q][0], acc[q][1], acc[q][2], acc[q][3]);
        *(float4*)(cp + 4) = make_float4(acc[q][4], acc[q][5], acc[q][6], acc[q][7]);
    }
}

// ---------------- K3b: k LN + dot with qn, reduce over n -> sw[2][512] ----------------
__global__ __launch_bounds__(256) void k3b_sw(const float* __restrict__ kraw,
                                              const float* __restrict__ qn,
                                              const float* __restrict__ kg,
                                              const float* __restrict__ kb,
                                              float* __restrict__ sw) {
    int s    = blockIdx.x;
    int w    = threadIdx.x >> 6;
    int lane = threadIdx.x & 63;
    float gv = kg[lane], bv = kb[lane];
    float acc0 = 0.f, acc1 = 0.f;
    for (int n = w; n < 384; n += 4) {
        const float* row = kraw + ((size_t)s * 384 + n) * 128;
        #pragma unroll
        for (int tt = 0; tt < 2; ++tt) {
            float v = row[tt * 64 + lane];
            float sum = v;
            #pragma unroll
            for (int m = 1; m < 64; m <<= 1) sum += __shfl_xor(sum, m);
            float mean = sum * (1.0f / 64.0f);
            float dv = v - mean;
            float sq = dv * dv;
            #pragma unroll
            for (int m = 1; m < 64; m <<= 1) sq += __shfl_xor(sq, m);
            float r  = rsqrtf(sq * (1.0f / 64.0f) + 1e-5f);
            float kn = dv * r * gv + bv;
            float p  = kn * qn[(size_t)(tt * 384 + n) * 64 + lane];
            #pragma unroll
            for (int m = 1; m < 64; m <<= 1) p += __shfl_xor(p, m);
            if (tt == 0) acc0 += p; else acc1 += p;
        }
    }
    __shared__ float red[8];
    if (lane == 0) { red[w] = acc0; red[4 + w] = acc1; }
    __syncthreads();
    if (threadIdx.x == 0) {
        float t0 = red[0] + red[1] + red[2] + red[3];
        float t1 = red[4] + red[5] + red[6] + red[7];
        sw[s]       = t0 * 0.125f / 384.0f;
        sw[512 + s] = t1 * 0.125f / 384.0f;
    }
}

// ---------------- K4: lambda, softmax over s, sqrt weights ----------------
__global__ __launch_bounds__(512) void k4_softmax(const float* __restrict__ sw,
                                                  const float* __restrict__ lq1,
                                                  const float* __restrict__ lk1,
                                                  const float* __restrict__ lq2,
                                                  const float* __restrict__ lk2,
                                                  float* __restrict__ wsq) {
    int s = threadIdx.x;
    float l1 = 0.f, l2 = 0.f;
    for (int i = 0; i < 64; ++i) { l1 += lq1[i] * lk1[i]; l2 += lq2[i] * lk2[i]; }
    float lam = expf(l1) - expf(l2) + 1.0f;
    float v = sw[s] - lam * sw[512 + s];
    __shared__ float red[512];
    red[s] = v;
    __syncthreads();
    for (int off = 256; off > 0; off >>= 1) {
        if (s < off) red[s] = fmaxf(red[s], red[s + off]);
        __syncthreads();
    }
    float mx = red[0];
    __syncthreads();
    float e = expf(v - mx);
    red[s] = e;
    __syncthreads();
    for (int off = 256; off > 0; off >>= 1) {
        if (s < off) red[s] += red[s + off];
        __syncthreads();
    }
    wsq[s] = sqrtf(e / red[0] + 1e-32f);
}

// ---------------- K5: build A[(i*32+c)][s], B[(i*32+c)][s] with sqrt-weight ----------------
__global__ __launch_bounds__(256) void k5_ab(const float* __restrict__ x,
                                             const float* __restrict__ Wl,
                                             const float* __restrict__ Wr,
                                             const float* __restrict__ wsq,
                                             float* __restrict__ Aout,
                                             float* __restrict__ Bout) {
    int i  = blockIdx.x;
    int s0 = blockIdx.y * 64;
    int t  = threadIdx.x;
    __shared__ __align__(16) float wl[2048], wr[2048];
    __shared__ float xT[64][69];
    ((float4*)wl)[t * 2]     = ((const float4*)Wl)[t * 2];
    ((float4*)wl)[t * 2 + 1] = ((const float4*)Wl)[t * 2 + 1];
    ((float4*)wr)[t * 2]     = ((const float4*)Wr)[t * 2];
    ((float4*)wr)[t * 2 + 1] = ((const float4*)Wr)[t * 2 + 1];
    {
        int s_l = t >> 2, d0 = (t & 3) * 16;
        const float* xr = x + ((size_t)(s0 + s_l) * 384 + i) * 64 + d0;
        #pragma unroll
        for (int j = 0; j < 4; ++j) {
            float4 v = *(const float4*)(xr + j * 4);
            xT[d0 + j * 4 + 0][s_l] = v.x; xT[d0 + j * 4 + 1][s_l] = v.y;
            xT[d0 + j * 4 + 2][s_l] = v.z; xT[d0 + j * 4 + 3][s_l] = v.w;
        }
    }
    __syncthreads();
    int c = t >> 3, so = (t & 7) * 8;
    float aa[8] = {}, bb2[8] = {};
    #pragma unroll 8
    for (int d = 0; d < 64; ++d) {
        float wlv = wl[c * 64 + d], wrv = wr[c * 64 + d];
        #pragma unroll
        for (int q = 0; q < 8; ++q) {
            float xv = xT[d][so + q];
            aa[q]  += xv * wlv;
            bb2[q] += xv * wrv;
        }
    }
    #pragma unroll
    for (int q = 0; q < 8; ++q) {
        float wq = wsq[s0 + so + q];
        aa[q] *= wq; bb2[q] *= wq;
    }
    float* ap = Aout + ((size_t)i * 32 + c) * 512 + s0 + so;
    float* bp = Bout + ((size_t)i * 32 + c) * 512 + s0 + so;
    *(float4*)ap       = make_float4(aa[0], aa[1], aa[2], aa[3]);
    *(float4*)(ap + 4) = make_float4(aa[4], aa[5], aa[6], aa[7]);
    *(float4*)bp       = make_float4(bb2[0], bb2[1], bb2[2], bb2[3]);
    *(float4*)(bp + 4) = make_float4(bb2[4], bb2[5], bb2[6], bb2[7]);
}

// ---------------- GEMM2: proj @ Wp^T + bias + SwiGLU, gathered A ----------------
// M rows are pairs (i*48 + jl) for the current chunk, N=256 full (val+gate in-block).
__global__ __launch_bounds__(256) void gemm2_swiglu(const float* __restrict__ OUTER,
                                                    const float* __restrict__ Wp,
                                                    const float* __restrict__ bp,
                                                    float* __restrict__ out, int jc) {
    __shared__ float AsT[32][68];
    __shared__ float BsT[32][260];
    __shared__ float gateLds[64][132];
    int t  = threadIdx.x;
    int m0 = blockIdx.x * 64;
    int tr = t >> 5, tc = t & 31;
    float acc[8][8] = {};
    for (int k0 = 0; k0 < 1024; k0 += 32) {
        int c = k0 >> 5;
        {   // stage A (gather): 64 pair-rows x 32 k (k = c*32 + e)
            int row = t >> 2;
            int kb  = (t & 3) * 8;
            int pg  = m0 + row;
            int i   = pg / 48, jl = pg % 48;
            const float* src = OUTER + ((size_t)i * 32 + c) * 1536 + jl * 32 + kb;
            #pragma unroll
            for (int l = 0; l < 2; ++l) {
                float4 v = *(const float4*)(src + l * 4);
                int kx = kb + l * 4;
                AsT[kx + 0][row] = v.x; AsT[kx + 1][row] = v.y;
                AsT[kx + 2][row] = v.z; AsT[kx + 3][row] = v.w;
            }
        }
        {   // stage B: Wp[256][k0..k0+32]
            int kb = (t & 7) * 4;
            #pragma unroll
            for (int l = 0; l < 8; ++l) {
                int nrow = l * 32 + (t >> 3);
                float4 v = *(const float4*)(Wp + (size_t)nrow * 1024 + k0 + kb);
                BsT[kb + 0][nrow] = v.x; BsT[kb + 1][nrow] = v.y;
                BsT[kb + 2][nrow] = v.z; BsT[kb + 3][nrow] = v.w;
            }
        }
        __syncthreads();
        #pragma unroll 4
        for (int k = 0; k < 32; ++k) {
            float a[8], b[8];
            *(float4*)&a[0] = *(const float4*)&AsT[k][tr * 8];
            *(float4*)&a[4] = *(const float4*)&AsT[k][tr * 8 + 4];
            *(float4*)&b[0] = *(const float4*)&BsT[k][tc * 8];
            *(float4*)&b[4] = *(const float4*)&BsT[k][tc * 8 + 4];
            #pragma unroll
            for (int q = 0; q < 8; ++q)
                #pragma unroll
                for (int j = 0; j < 8; ++j)
                    acc[q][j] += a[q] * b[j];
        }
        __syncthreads();
    }
    // SwiGLU: cols tc*8+j; gate half = cols >= 128 (tc >= 16)
    if (tc >= 16) {
        #pragma unroll
        for (int q = 0; q < 8; ++q)
            #pragma unroll
            for (int j = 0; j < 8; ++j)
                gateLds[tr * 8 + q][(tc - 16) * 8 + j] = acc[q][j] + bp[tc * 8 + j];
    }
    __syncthreads();
    if (tc < 16) {
        #pragma unroll
        for (int q = 0; q < 8; ++q) {
            int pg = m0 + tr * 8 + q;
            int i = pg / 48, jl = pg % 48;
            float* op = out + ((size_t)i * 384 + (jc * 48 + jl)) * 128 + tc * 8;
            float vals[8];
            #pragma unroll
            for (int j = 0; j < 8; ++j) {
                float gg = gateLds[tr * 8 + q][tc * 8 + j];
                float vv = acc[q][j] + bp[tc * 8 + j];
                vals[j] = vv * gg / (1.0f + expf(-gg));
            }
            *(float4*)op       = make_float4(vals[0], vals[1], vals[2], vals[3]);
            *(float4*)(op + 4) = make_float4(vals[4], vals[5], vals[6], vals[7]);
        }
    }
}

extern "C" void kernel_launch(void* const* d_in, const int* in_sizes, int n_in,
                              void* d_out, int out_size, void* d_ws, size_t ws_size,
                              hipStream_t stream) {
    const float* msa  = (const float*)d_in[0];
    const float* ln_g = (const float*)d_in[1];
    const float* ln_b = (const float*)d_in[2];
    const float* Wq   = (const float*)d_in[3];
    const float* Wk   = (const float*)d_in[4];
    const float* qn_g = (const float*)d_in[5];
    const float* qn_b = (const float*)d_in[6];
    const float* kn_g = (const float*)d_in[7];
    const float* kn_b = (const float*)d_in[8];
    const float* lq1  = (const float*)d_in[9];
    const float* lk1  = (const float*)d_in[10];
    const float* lq2  = (const float*)d_in[11];
    const float* lk2  = (const float*)d_in[12];
    const float* Wl   = (const float*)d_in[13];
    const float* Wr   = (const float*)d_in[14];
    const float* Wp   = (const float*)d_in[15];
    const float* bp   = (const float*)d_in[16];
    float* out = (float*)d_out;
    float* ws  = (float*)d_ws;

    float* x       = ws + WS_X;
    float* Aw      = ws + WS_A;
    float* Bw      = ws + WS_B;
    float* qn      = ws + WS_QN;
    float* sw      = ws + WS_SW;
    float* wsq     = ws + WS_WSQ;
    float* scratch = ws + WS_SCRATCH;   // kraw, later outer

    // K1: LayerNorm  (196608 rows, 4 per block)
    k1_ln<<<49152, 256, 0, stream>>>(msa, ln_g, ln_b, x);
    // K2: q proj + LN
    k2_q<<<384, 128, 0, stream>>>(x, Wq, qn_g, qn_b, qn);
    // K3a: kraw = x @ Wk^T   (M=196608, N=128, K=64)
    gemm_nt<<<dim3(1536, 1), 256, 0, stream>>>(x, Wk, scratch, 64, 64, 64, 128);
    // K3b: k LN + dot q + reduce over n
    k3b_sw<<<512, 256, 0, stream>>>(scratch, qn, kn_g, kn_b, sw);
    // K4: lambda + softmax + sqrt
    k4_softmax<<<1, 512, 0, stream>>>(sw, lq1, lk1, lq2, lk2, wsq);
    // K5: A/B build
    k5_ab<<<dim3(384, 8), 256, 0, stream>>>(x, Wl, Wr, wsq, Aw, Bw);
    // Chunked outer-product + projection + SwiGLU
    for (int jc = 0; jc < NCHUNK; ++jc) {
        // GEMM1: outer chunk [12288][1536] = Aw @ (Bw chunk)^T   K=512
        gemm_nt<<<dim3(96, 12), 256, 0, stream>>>(
            Aw, Bw + (size_t)jc * NCCOLS * 512, scratch, 512, 512, 512, NCCOLS);
        // GEMM2: (pairs x 1024) @ Wp^T + bias + SwiGLU -> out
        gemm2_swiglu<<<dim3(288, 1), 256, 0, stream>>>(scratch, Wp, bp, out, jc);
    }
}

// Round 2
// 1814.839 us; speedup vs baseline: 2.1771x; 2.1771x over previous
//
#include <hip/hip_runtime.h>
#include <hip/hip_bf16.h>
#include <math.h>

// B=1, S=512, N=384, D=64, H=32, DP=128, DQK=64
// ws layout (float offsets)
#define WS_X        0u          // x f32 [196608][64]                 = 12582912
#define WS_AEXT     12582912u   // Aext bf16 [12288][1024] (AH|AL)    =  6291456 f
#define WS_BEXT     18874368u   // Bext bf16 [12288][1024] (BH|BL)    =  6291456 f
#define WS_QN       25165824u   // [2][384][64]                       =    49152
#define WS_SW       25214976u   // [2][512]
#define WS_WSQ      25216000u   // [512]
#define WS_BPP      25216512u   // [256]
#define WS_WPEXT    25216768u   // WpExt bf16 [256][2048] (WH|WL)     =   262144 f
#define WS_BIG      25478912u   // kraw half [98304][128] f32 (12.58M f) THEN OutHL u32 [12288][1536] (18.87M f)
// total = 25478912 + 18874368 = 44353280 floats = 177.4 MB (round-1 used 201.5 MB OK)

typedef __attribute__((ext_vector_type(8))) short bf16x8;
typedef __attribute__((ext_vector_type(4))) float f32x4;

__device__ __forceinline__ unsigned short f2b(float x) {
    __hip_bfloat16 b = __float2bfloat16(x);
    return *reinterpret_cast<unsigned short*>(&b);
}
__device__ __forceinline__ float b2f(unsigned short u) {
    __hip_bfloat16 b = *reinterpret_cast<__hip_bfloat16*>(&u);
    return __bfloat162float(b);
}

#define GLDS(g, l) __builtin_amdgcn_global_load_lds(                                   \
    (const __attribute__((address_space(1))) unsigned int*)(g),                        \
    (__attribute__((address_space(3))) unsigned int*)(l), 16, 0, 0)

// ---------------- K1: LayerNorm over D=64, one wave per row ----------------
__global__ __launch_bounds__(256) void k1_ln(const float* __restrict__ msa,
                                             const float* __restrict__ g,
                                             const float* __restrict__ bb,
                                             float* __restrict__ x) {
    int row  = blockIdx.x * 4 + (threadIdx.x >> 6);
    int lane = threadIdx.x & 63;
    float v = msa[(size_t)row * 64 + lane];
    float sum = v;
    #pragma unroll
    for (int m = 1; m < 64; m <<= 1) sum += __shfl_xor(sum, m);
    float mean = sum * (1.0f / 64.0f);
    float dv = v - mean;
    float sq = dv * dv;
    #pragma unroll
    for (int m = 1; m < 64; m <<= 1) sq += __shfl_xor(sq, m);
    float r = rsqrtf(sq * (1.0f / 64.0f) + 1e-5f);
    x[(size_t)row * 64 + lane] = dv * r * g[lane] + bb[lane];
}

// ---------------- K2: q projection (s=0 rows) + LN ----------------
__global__ __launch_bounds__(128) void k2_q(const float* __restrict__ x,
                                            const float* __restrict__ Wq,
                                            const float* __restrict__ qg,
                                            const float* __restrict__ qb,
                                            float* __restrict__ qn) {
    int n = blockIdx.x;
    int t = threadIdx.x >> 6;
    int d = threadIdx.x & 63;
    const float* xr = x + (size_t)n * 64;
    const float* w  = Wq + (size_t)(t * 64 + d) * 64;
    float acc = 0.f;
    #pragma unroll 8
    for (int dd = 0; dd < 64; ++dd) acc += xr[dd] * w[dd];
    float sum = acc;
    #pragma unroll
    for (int m = 1; m < 64; m <<= 1) sum += __shfl_xor(sum, m);
    float mean = sum * (1.0f / 64.0f);
    float dv = acc - mean;
    float sq = dv * dv;
    #pragma unroll
    for (int m = 1; m < 64; m <<= 1) sq += __shfl_xor(sq, m);
    float r = rsqrtf(sq * (1.0f / 64.0f) + 1e-5f);
    qn[(size_t)(t * 384 + n) * 64 + d] = dv * r * qg[d] + qb[d];
}

// ---------------- fp32 NT GEMM (kept for K3a only: x @ Wk^T) ----------------
__global__ __launch_bounds__(256) void gemm_nt(const float* __restrict__ A,
                                               const float* __restrict__ Bm,
                                               float* __restrict__ C,
                                               int K, int lda, int ldb, int ldc) {
    __shared__ float AsT[32][132];
    __shared__ float BsT[32][132];
    int t  = threadIdx.x;
    int m0 = blockIdx.x * 128, n0 = blockIdx.y * 128;
    int tr = t >> 4, tc = t & 15;
    float acc[8][8] = {};
    int rrow = t >> 3;
    int kk   = (t & 7) * 4;
    for (int k0 = 0; k0 < K; k0 += 32) {
        #pragma unroll
        for (int l = 0; l < 4; ++l) {
            int row = rrow + 32 * l;
            float4 va = *(const float4*)(A + (size_t)(m0 + row) * lda + k0 + kk);
            AsT[kk + 0][row] = va.x; AsT[kk + 1][row] = va.y;
            AsT[kk + 2][row] = va.z; AsT[kk + 3][row] = va.w;
            float4 vb = *(const float4*)(Bm + (size_t)(n0 + row) * ldb + k0 + kk);
            BsT[kk + 0][row] = vb.x; BsT[kk + 1][row] = vb.y;
            BsT[kk + 2][row] = vb.z; BsT[kk + 3][row] = vb.w;
        }
        __syncthreads();
        #pragma unroll 4
        for (int k = 0; k < 32; ++k) {
            float a[8], b[8];
            *(float4*)&a[0] = *(const float4*)&AsT[k][tr * 8];
            *(float4*)&a[4] = *(const float4*)&AsT[k][tr * 8 + 4];
            *(float4*)&b[0] = *(const float4*)&BsT[k][tc * 8];
            *(float4*)&b[4] = *(const float4*)&BsT[k][tc * 8 + 4];
            #pragma unroll
            for (int q = 0; q < 8; ++q)
                #pragma unroll
                for (int j = 0; j < 8; ++j)
                    acc[q][j] += a[q] * b[j];
        }
        __syncthreads();
    }
    #pragma unroll
    for (int q = 0; q < 8; ++q) {
        float* cp = C + (size_t)(m0 + tr * 8 + q) * ldc + n0 + tc * 8;
        *(float4*)cp       = make_float4(acc[q][0], acc[q][1], acc[q][2], acc[q][3]);
        *(float4*)(cp + 4) = make_float4(acc[q][4], acc[q][5], acc[q][6], acc[q][7]);
    }
}

// ---------------- K3b: k LN + dot with qn, reduce over n -> sw[2][512] ----------------
__global__ __launch_bounds__(256) void k3b_sw(const float* __restrict__ kraw,
                                              const float* __restrict__ qn,
                                              const float* __restrict__ kg,
                                              const float* __restrict__ kb,
                                              float* __restrict__ sw, int sc) {
    int sl   = blockIdx.x;                 // local s within chunk
    int s    = sc * 256 + sl;
    int w    = threadIdx.x >> 6;
    int lane = threadIdx.x & 63;
    float gv = kg[lane], bv = kb[lane];
    float acc0 = 0.f, acc1 = 0.f;
    for (int n = w; n < 384; n += 4) {
        const float* row = kraw + ((size_t)sl * 384 + n) * 128;
        #pragma unroll
        for (int tt = 0; tt < 2; ++tt) {
            float v = row[tt * 64 + lane];
            float sum = v;
            #pragma unroll
            for (int m = 1; m < 64; m <<= 1) sum += __shfl_xor(sum, m);
            float mean = sum * (1.0f / 64.0f);
            float dv = v - mean;
            float sq = dv * dv;
            #pragma unroll
            for (int m = 1; m < 64; m <<= 1) sq += __shfl_xor(sq, m);
            float r  = rsqrtf(sq * (1.0f / 64.0f) + 1e-5f);
            float kn = dv * r * gv + bv;
            float p  = kn * qn[(size_t)(tt * 384 + n) * 64 + lane];
            #pragma unroll
            for (int m = 1; m < 64; m <<= 1) p += __shfl_xor(p, m);
            if (tt == 0) acc0 += p; else acc1 += p;
        }
    }
    __shared__ float red[8];
    if (lane == 0) { red[w] = acc0; red[4 + w] = acc1; }
    __syncthreads();
    if (threadIdx.x == 0) {
        float t0 = red[0] + red[1] + red[2] + red[3];
        float t1 = red[4] + red[5] + red[6] + red[7];
        sw[s]       = t0 * 0.125f / 384.0f;
        sw[512 + s] = t1 * 0.125f / 384.0f;
    }
}

// ---------------- K4: lambda, softmax over s, sqrt weights ----------------
__global__ __launch_bounds__(512) void k4_softmax(const float* __restrict__ sw,
                                                  const float* __restrict__ lq1,
                                                  const float* __restrict__ lk1,
                                                  const float* __restrict__ lq2,
                                                  const float* __restrict__ lk2,
                                                  float* __restrict__ wsq) {
    int s = threadIdx.x;
    float l1 = 0.f, l2 = 0.f;
    for (int i = 0; i < 64; ++i) { l1 += lq1[i] * lk1[i]; l2 += lq2[i] * lk2[i]; }
    float lam = expf(l1) - expf(l2) + 1.0f;
    float v = sw[s] - lam * sw[512 + s];
    __shared__ float red[512];
    red[s] = v;
    __syncthreads();
    for (int off = 256; off > 0; off >>= 1) {
        if (s < off) red[s] = fmaxf(red[s], red[s + off]);
        __syncthreads();
    }
    float mx = red[0];
    __syncthreads();
    float e = expf(v - mx);
    red[s] = e;
    __syncthreads();
    for (int off = 256; off > 0; off >>= 1) {
        if (s < off) red[s] += red[s + off];
        __syncthreads();
    }
    wsq[s] = sqrtf(e / red[0] + 1e-32f);
}

// ---------------- K5: build Aext/Bext (hi/lo bf16 split, K-sections) ----------------
__global__ __launch_bounds__(256) void k5_ab(const float* __restrict__ x,
                                             const float* __restrict__ Wl,
                                             const float* __restrict__ Wr,
                                             const float* __restrict__ wsq,
                                             unsigned short* __restrict__ Aext,
                                             unsigned short* __restrict__ Bext) {
    int i  = blockIdx.x;
    int s0 = blockIdx.y * 64;
    int t  = threadIdx.x;
    __shared__ __align__(16) float wl[2048], wr[2048];
    __shared__ float xT[64][69];
    ((float4*)wl)[t * 2]     = ((const float4*)Wl)[t * 2];
    ((float4*)wl)[t * 2 + 1] = ((const float4*)Wl)[t * 2 + 1];
    ((float4*)wr)[t * 2]     = ((const float4*)Wr)[t * 2];
    ((float4*)wr)[t * 2 + 1] = ((const float4*)Wr)[t * 2 + 1];
    {
        int s_l = t >> 2, d0 = (t & 3) * 16;
        const float* xr = x + ((size_t)(s0 + s_l) * 384 + i) * 64 + d0;
        #pragma unroll
        for (int j = 0; j < 4; ++j) {
            float4 v = *(const float4*)(xr + j * 4);
            xT[d0 + j * 4 + 0][s_l] = v.x; xT[d0 + j * 4 + 1][s_l] = v.y;
            xT[d0 + j * 4 + 2][s_l] = v.z; xT[d0 + j * 4 + 3][s_l] = v.w;
        }
    }
    __syncthreads();
    int c = t >> 3, so = (t & 7) * 8;
    float aa[8] = {}, bb2[8] = {};
    #pragma unroll 8
    for (int d = 0; d < 64; ++d) {
        float wlv = wl[c * 64 + d], wrv = wr[c * 64 + d];
        #pragma unroll
        for (int q = 0; q < 8; ++q) {
            float xv = xT[d][so + q];
            aa[q]  += xv * wlv;
            bb2[q] += xv * wrv;
        }
    }
    #pragma unroll
    for (int q = 0; q < 8; ++q) {
        float wq = wsq[s0 + so + q];
        aa[q] *= wq; bb2[q] *= wq;
    }
    size_t row = (size_t)i * 32 + c;
    {
        unsigned short h[8]; unsigned short l[8];
        #pragma unroll
        for (int q = 0; q < 8; ++q) { h[q] = f2b(aa[q]); l[q] = f2b(aa[q] - b2f(h[q])); }
        uint4 H = make_uint4((unsigned)h[0] | ((unsigned)h[1] << 16), (unsigned)h[2] | ((unsigned)h[3] << 16),
                             (unsigned)h[4] | ((unsigned)h[5] << 16), (unsigned)h[6] | ((unsigned)h[7] << 16));
        uint4 L = make_uint4((unsigned)l[0] | ((unsigned)l[1] << 16), (unsigned)l[2] | ((unsigned)l[3] << 16),
                             (unsigned)l[4] | ((unsigned)l[5] << 16), (unsigned)l[6] | ((unsigned)l[7] << 16));
        *(uint4*)&Aext[row * 1024 + s0 + so]       = H;
        *(uint4*)&Aext[row * 1024 + 512 + s0 + so] = L;
    }
    {
        unsigned short h[8]; unsigned short l[8];
        #pragma unroll
        for (int q = 0; q < 8; ++q) { h[q] = f2b(bb2[q]); l[q] = f2b(bb2[q] - b2f(h[q])); }
        uint4 H = make_uint4((unsigned)h[0] | ((unsigned)h[1] << 16), (unsigned)h[2] | ((unsigned)h[3] << 16),
                             (unsigned)h[4] | ((unsigned)h[5] << 16), (unsigned)h[6] | ((unsigned)h[7] << 16));
        uint4 L = make_uint4((unsigned)l[0] | ((unsigned)l[1] << 16), (unsigned)l[2] | ((unsigned)l[3] << 16),
                             (unsigned)l[4] | ((unsigned)l[5] << 16), (unsigned)l[6] | ((unsigned)l[7] << 16));
        *(uint4*)&Bext[row * 1024 + s0 + so]       = H;
        *(uint4*)&Bext[row * 1024 + 512 + s0 + so] = L;
    }
}

// ---------------- prep: WpExt [256][2048] bf16 (interleaved val/gate rows; H|L) + bpP ----------------
__global__ __launch_bounds__(256) void prep_wp(const float* __restrict__ Wp,
                                               const float* __restrict__ bp,
                                               unsigned short* __restrict__ WpE,
                                               float* __restrict__ bpP) {
    int idx = blockIdx.x * 256 + threadIdx.x;     // 2048 blocks -> 524288
    int row = idx >> 11;
    int kk  = idx & 2047;
    int u   = (row & 1) ? 128 + (row >> 1) : (row >> 1);
    int k   = kk & 1023;
    float w = Wp[(size_t)u * 1024 + k];
    unsigned short h = f2b(w);
    WpE[(size_t)row * 2048 + kk] = (kk < 1024) ? h : f2b(w - b2f(h));
    if (blockIdx.x == 0) {
        int tt = threadIdx.x;
        bpP[tt] = bp[(tt & 1) ? 128 + (tt >> 1) : (tt >> 1)];
    }
}

// ---------------- GEMM1 (MFMA bf16x3): C = Aext . Bext_chunk^T -> packed hi/lo u32 ----------------
// A sections over K: [AH, AL, AH]; B sections: [BH, BH, BL]  (512 logical K each)
__global__ __launch_bounds__(256) void gemm1_mfma(const unsigned short* __restrict__ A,
                                                  const unsigned short* __restrict__ B,
                                                  unsigned int* __restrict__ OutHL) {
    __shared__ __align__(16) unsigned short As[128 * 32];
    __shared__ __align__(16) unsigned short Bs[128 * 32];
    const int t = threadIdx.x;
    const int wave = t >> 6, lane = t & 63;
    const int m0 = blockIdx.x * 128, n0 = blockIdx.y * 128;
    const int wm = (wave & 1) * 64, wn = (wave >> 1) * 64;
    const int kgrp = lane >> 4, rl = lane & 15;
    f32x4 acc[4][4] = {};

    for (int kk0 = 0; kk0 < 1536; kk0 += 32) {
        const int sec = kk0 >> 9;
        const int kl  = kk0 & 511;
        const int scolA = (sec == 1) ? 512 + kl : kl;
        const int scolB = (sec == 2) ? 512 + kl : kl;
        #pragma unroll
        for (int is = 0; is < 2; ++is) {
            const int u   = wave * 128 + is * 64 + lane;
            const int row = u >> 2;
            const int blk = (u & 3) ^ ((u >> 3) & 3);   // pre-swizzled source (read-side XOR dec-conflict)
            GLDS(A + (size_t)(m0 + row) * 1024 + scolA + blk * 8, As + (size_t)(wave * 128 + is * 64) * 8);
            GLDS(B + (size_t)(n0 + row) * 1024 + scolB + blk * 8, Bs + (size_t)(wave * 128 + is * 64) * 8);
        }
        __syncthreads();
        bf16x8 aF[4], bF[4];
        #pragma unroll
        for (int f = 0; f < 4; ++f) {
            int ra = wm + f * 16 + rl;
            aF[f] = *(const bf16x8*)&As[ra * 32 + (kgrp ^ ((ra >> 1) & 3)) * 8];
            int rb = wn + f * 16 + rl;
            bF[f] = *(const bf16x8*)&Bs[rb * 32 + (kgrp ^ ((rb >> 1) & 3)) * 8];
        }
        #pragma unroll
        for (int mf = 0; mf < 4; ++mf)
            #pragma unroll
            for (int nf = 0; nf < 4; ++nf)
                acc[mf][nf] = __builtin_amdgcn_mfma_f32_16x16x32_bf16(aF[mf], bF[nf], acc[mf][nf], 0, 0, 0);
        __syncthreads();
    }
    const int rb0 = (lane >> 4) * 4;
    #pragma unroll
    for (int mf = 0; mf < 4; ++mf)
        #pragma unroll
        for (int nf = 0; nf < 4; ++nf) {
            int n = n0 + wn + nf * 16 + rl;
            #pragma unroll
            for (int r = 0; r < 4; ++r) {
                int m = m0 + wm + mf * 16 + rb0 + r;
                float v = acc[mf][nf][r];
                unsigned short h  = f2b(v);
                unsigned short lo = f2b(v - b2f(h));
                OutHL[(size_t)m * 1536 + n] = (unsigned)h | ((unsigned)lo << 16);
            }
        }
}

// ---------------- GEMM2 (MFMA bf16x3): pairs x WpExt^T + bias + SwiGLU -> out ----------------
// A sections: [OH, OL, OH] (gathered from packed OutHL); B sections: [WH, WH, WL]
__global__ __launch_bounds__(256) void gemm2_mfma(const unsigned int* __restrict__ OutHL,
                                                  const unsigned short* __restrict__ WpE,
                                                  const float* __restrict__ bpP,
                                                  float* __restrict__ out, int jc) {
    __shared__ __align__(16) unsigned short As[128 * 32];
    __shared__ __align__(16) unsigned short Bs[128 * 32];
    const int t = threadIdx.x;
    const int wave = t >> 6, lane = t & 63;
    const int m0 = blockIdx.x * 128, n0 = blockIdx.y * 128;
    const int wm = (wave & 1) * 64, wn = (wave >> 1) * 64;
    const int kgrp = lane >> 4, rl = lane & 15;
    f32x4 acc[4][4] = {};

    for (int kk0 = 0; kk0 < 3072; kk0 += 32) {
        const int sec = kk0 >> 10;
        const int kl  = kk0 & 1023;
        const int c   = kl >> 5;
        const int shift = (sec == 1) ? 16 : 0;
        {   // B stage via global_load_lds
            const int scolB = (sec == 2) ? 1024 + kl : kl;
            #pragma unroll
            for (int is = 0; is < 2; ++is) {
                const int u   = wave * 128 + is * 64 + lane;
                const int row = u >> 2;
                const int blk = (u & 3) ^ ((u >> 3) & 3);
                GLDS(WpE + (size_t)(n0 + row) * 2048 + scolB + blk * 8, Bs + (size_t)(wave * 128 + is * 64) * 8);
            }
        }
        // A stage: gather hi/lo halves from packed OutHL, reg-staged
        #pragma unroll
        for (int iu = 0; iu < 2; ++iu) {
            const int u    = t * 2 + iu;
            const int row  = u >> 2;
            const int blk  = u & 3;
            const int pblk = blk ^ ((row >> 1) & 3);
            const int pg = m0 + row;
            const int i = pg / 48, jl = pg - i * 48;
            const unsigned int* src = OutHL + (size_t)(i * 32 + c) * 1536 + jl * 32 + blk * 8;
            uint4 p0 = *(const uint4*)src;
            uint4 p1 = *(const uint4*)(src + 4);
            unsigned w0 = ((p0.x >> shift) & 0xffffu) | (((p0.y >> shift) & 0xffffu) << 16);
            unsigned w1 = ((p0.z >> shift) & 0xffffu) | (((p0.w >> shift) & 0xffffu) << 16);
            unsigned w2 = ((p1.x >> shift) & 0xffffu) | (((p1.y >> shift) & 0xffffu) << 16);
            unsigned w3 = ((p1.z >> shift) & 0xffffu) | (((p1.w >> shift) & 0xffffu) << 16);
            *(uint4*)&As[row * 32 + pblk * 8] = make_uint4(w0, w1, w2, w3);
        }
        __syncthreads();
        bf16x8 aF[4], bF[4];
        #pragma unroll
        for (int f = 0; f < 4; ++f) {
            int ra = wm + f * 16 + rl;
            aF[f] = *(const bf16x8*)&As[ra * 32 + (kgrp ^ ((ra >> 1) & 3)) * 8];
            int rb = wn + f * 16 + rl;
            bF[f] = *(const bf16x8*)&Bs[rb * 32 + (kgrp ^ ((rb >> 1) & 3)) * 8];
        }
        #pragma unroll
        for (int mf = 0; mf < 4; ++mf)
            #pragma unroll
            for (int nf = 0; nf < 4; ++nf)
                acc[mf][nf] = __builtin_amdgcn_mfma_f32_16x16x32_bf16(aF[mf], bF[nf], acc[mf][nf], 0, 0, 0);
        __syncthreads();
    }
    // epilogue: val/gate pairing via shfl_xor(1), SwiGLU, store
    const int rb0 = (lane >> 4) * 4;
    const int parity = rl & 1;
    #pragma unroll
    for (int nf = 0; nf < 4; ++nf) {
        const int np = n0 + wn + nf * 16 + rl;
        const float bias = bpP[np];
        const int ocol = np >> 1;
        #pragma unroll
        for (int mf = 0; mf < 4; ++mf) {
            #pragma unroll
            for (int r = 0; r < 4; ++r) {
                float own = acc[mf][nf][r] + bias;
                float oth = __shfl_xor(own, 1);
                float v = parity ? oth : own;
                float g = parity ? own : oth;
                float res = v * (g / (1.0f + expf(-g)));
                if (parity == (r >> 1)) {
                    int pg = m0 + wm + mf * 16 + rb0 + r;
                    int i = pg / 48, jl = pg - i * 48;
                    out[((size_t)i * 384 + jc * 48 + jl) * 128 + ocol] = res;
                }
            }
        }
    }
}

extern "C" void kernel_launch(void* const* d_in, const int* in_sizes, int n_in,
                              void* d_out, int out_size, void* d_ws, size_t ws_size,
                              hipStream_t stream) {
    const float* msa  = (const float*)d_in[0];
    const float* ln_g = (const float*)d_in[1];
    const float* ln_b = (const float*)d_in[2];
    const float* Wq   = (const float*)d_in[3];
    const float* Wk   = (const float*)d_in[4];
    const float* qn_g = (const float*)d_in[5];
    const float* qn_b = (const float*)d_in[6];
    const float* kn_g = (const float*)d_in[7];
    const float* kn_b = (const float*)d_in[8];
    const float* lq1  = (const float*)d_in[9];
    const float* lk1  = (const float*)d_in[10];
    const float* lq2  = (const float*)d_in[11];
    const float* lk2  = (const float*)d_in[12];
    const float* Wl   = (const float*)d_in[13];
    const float* Wr   = (const float*)d_in[14];
    const float* Wp   = (const float*)d_in[15];
    const float* bp   = (const float*)d_in[16];
    float* out = (float*)d_out;
    float* ws  = (float*)d_ws;

    float* x = ws + WS_X;
    unsigned short* AextS = (unsigned short*)(ws + WS_AEXT);
    unsigned short* BextS = (unsigned short*)(ws + WS_BEXT);
    float* qn  = ws + WS_QN;
    float* sw  = ws + WS_SW;
    float* wsq = ws + WS_WSQ;
    float* bpP = ws + WS_BPP;
    unsigned short* WpE = (unsigned short*)(ws + WS_WPEXT);
    float* kraw = ws + WS_BIG;
    unsigned int* OutHL = (unsigned int*)(ws + WS_BIG);

    prep_wp<<<2048, 256, 0, stream>>>(Wp, bp, WpE, bpP);
    k1_ln<<<49152, 256, 0, stream>>>(msa, ln_g, ln_b, x);
    k2_q<<<384, 128, 0, stream>>>(x, Wq, qn_g, qn_b, qn);
    for (int sc = 0; sc < 2; ++sc) {
        gemm_nt<<<dim3(768, 1), 256, 0, stream>>>(x + (size_t)sc * 98304 * 64, Wk, kraw, 64, 64, 64, 128);
        k3b_sw<<<256, 256, 0, stream>>>(kraw, qn, kn_g, kn_b, sw, sc);
    }
    k4_softmax<<<1, 512, 0, stream>>>(sw, lq1, lk1, lq2, lk2, wsq);
    k5_ab<<<dim3(384, 8), 256, 0, stream>>>(x, Wl, Wr, wsq, AextS, BextS);
    for (int jc = 0; jc < 8; ++jc) {
        gemm1_mfma<<<dim3(96, 12), 256, 0, stream>>>(AextS, BextS + (size_t)jc * 1536 * 1024, OutHL);
        gemm2_mfma<<<dim3(144, 2), 256, 0, stream>>>(OutHL, WpE, bpP, out, jc);
    }
}

// Round 3
// 1292.859 us; speedup vs baseline: 3.0561x; 1.4037x over previous
//
#include <hip/hip_runtime.h>
#include <hip/hip_bf16.h>
#include <math.h>

// B=1, S=512, N=384, D=64, H=32, DP=128, DQK=64
// ws layout (float offsets)
#define WS_X        0u          // x f32 [196608][64]                 = 12582912
#define WS_AEXT     12582912u   // Aext bf16 [12288][1024] (AH|AL)    =  6291456 f
#define WS_BEXT     18874368u   // Bext bf16 [12288][1024] (BH|BL)    =  6291456 f
#define WS_QN       25165824u   // [2][384][64]                       =    49152
#define WS_SW       25214976u   // [2][512]
#define WS_WSQ      25216000u   // [512]
#define WS_BPP      25216512u   // [256]
#define WS_WPF      25216768u   // WpF bf16 frag-layout [2][16][32][64][8] = 524288 shorts = 262144 f
#define WS_BIG      25478912u   // kraw half [98304][128] f32 = 12582912 f
// total = 38061824 floats = 152.2 MB (round-1 used 201.5 MB OK)

typedef __attribute__((ext_vector_type(8))) short bf16x8;
typedef __attribute__((ext_vector_type(4))) float f32x4;

union U4B8 { uint4 u4; unsigned u[4]; bf16x8 v; };

__device__ __forceinline__ unsigned short f2b(float x) {
    __hip_bfloat16 b = __float2bfloat16(x);
    return *reinterpret_cast<unsigned short*>(&b);
}
__device__ __forceinline__ float b2f(unsigned short u) {
    __hip_bfloat16 b = *reinterpret_cast<__hip_bfloat16*>(&u);
    return __bfloat162float(b);
}

#define GLDS(g, l) __builtin_amdgcn_global_load_lds(                                   \
    (const __attribute__((address_space(1))) unsigned int*)(g),                        \
    (__attribute__((address_space(3))) unsigned int*)(l), 16, 0, 0)

// ---------------- K1: LayerNorm over D=64, one wave per row ----------------
__global__ __launch_bounds__(256) void k1_ln(const float* __restrict__ msa,
                                             const float* __restrict__ g,
                                             const float* __restrict__ bb,
                                             float* __restrict__ x) {
    int row  = blockIdx.x * 4 + (threadIdx.x >> 6);
    int lane = threadIdx.x & 63;
    float v = msa[(size_t)row * 64 + lane];
    float sum = v;
    #pragma unroll
    for (int m = 1; m < 64; m <<= 1) sum += __shfl_xor(sum, m);
    float mean = sum * (1.0f / 64.0f);
    float dv = v - mean;
    float sq = dv * dv;
    #pragma unroll
    for (int m = 1; m < 64; m <<= 1) sq += __shfl_xor(sq, m);
    float r = rsqrtf(sq * (1.0f / 64.0f) + 1e-5f);
    x[(size_t)row * 64 + lane] = dv * r * g[lane] + bb[lane];
}

// ---------------- K2: q projection (s=0 rows) + LN ----------------
__global__ __launch_bounds__(128) void k2_q(const float* __restrict__ x,
                                            const float* __restrict__ Wq,
                                            const float* __restrict__ qg,
                                            const float* __restrict__ qb,
                                            float* __restrict__ qn) {
    int n = blockIdx.x;
    int t = threadIdx.x >> 6;
    int d = threadIdx.x & 63;
    const float* xr = x + (size_t)n * 64;
    const float* w  = Wq + (size_t)(t * 64 + d) * 64;
    float acc = 0.f;
    #pragma unroll 8
    for (int dd = 0; dd < 64; ++dd) acc += xr[dd] * w[dd];
    float sum = acc;
    #pragma unroll
    for (int m = 1; m < 64; m <<= 1) sum += __shfl_xor(sum, m);
    float mean = sum * (1.0f / 64.0f);
    float dv = acc - mean;
    float sq = dv * dv;
    #pragma unroll
    for (int m = 1; m < 64; m <<= 1) sq += __shfl_xor(sq, m);
    float r = rsqrtf(sq * (1.0f / 64.0f) + 1e-5f);
    qn[(size_t)(t * 384 + n) * 64 + d] = dv * r * qg[d] + qb[d];
}

// ---------------- fp32 NT GEMM (kept for K3a only: x @ Wk^T) ----------------
__global__ __launch_bounds__(256) void gemm_nt(const float* __restrict__ A,
                                               const float* __restrict__ Bm,
                                               float* __restrict__ C,
                                               int K, int lda, int ldb, int ldc) {
    __shared__ float AsT[32][132];
    __shared__ float BsT[32][132];
    int t  = threadIdx.x;
    int m0 = blockIdx.x * 128, n0 = blockIdx.y * 128;
    int tr = t >> 4, tc = t & 15;
    float acc[8][8] = {};
    int rrow = t >> 3;
    int kk   = (t & 7) * 4;
    for (int k0 = 0; k0 < K; k0 += 32) {
        #pragma unroll
        for (int l = 0; l < 4; ++l) {
            int row = rrow + 32 * l;
            float4 va = *(const float4*)(A + (size_t)(m0 + row) * lda + k0 + kk);
            AsT[kk + 0][row] = va.x; AsT[kk + 1][row] = va.y;
            AsT[kk + 2][row] = va.z; AsT[kk + 3][row] = va.w;
            float4 vb = *(const float4*)(Bm + (size_t)(n0 + row) * ldb + k0 + kk);
            BsT[kk + 0][row] = vb.x; BsT[kk + 1][row] = vb.y;
            BsT[kk + 2][row] = vb.z; BsT[kk + 3][row] = vb.w;
        }
        __syncthreads();
        #pragma unroll 4
        for (int k = 0; k < 32; ++k) {
            float a[8], b[8];
            *(float4*)&a[0] = *(const float4*)&AsT[k][tr * 8];
            *(float4*)&a[4] = *(const float4*)&AsT[k][tr * 8 + 4];
            *(float4*)&b[0] = *(const float4*)&BsT[k][tc * 8];
            *(float4*)&b[4] = *(const float4*)&BsT[k][tc * 8 + 4];
            #pragma unroll
            for (int q = 0; q < 8; ++q)
                #pragma unroll
                for (int j = 0; j < 8; ++j)
                    acc[q][j] += a[q] * b[j];
        }
        __syncthreads();
    }
    #pragma unroll
    for (int q = 0; q < 8; ++q) {
        float* cp = C + (size_t)(m0 + tr * 8 + q) * ldc + n0 + tc * 8;
        *(float4*)cp       = make_float4(acc[q][0], acc[q][1], acc[q][2], acc[q][3]);
        *(float4*)(cp + 4) = make_float4(acc[q][4], acc[q][5], acc[q][6], acc[q][7]);
    }
}

// ---------------- K3b: k LN + dot with qn, reduce over n -> sw[2][512] ----------------
__global__ __launch_bounds__(256) void k3b_sw(const float* __restrict__ kraw,
                                              const float* __restrict__ qn,
                                              const float* __restrict__ kg,
                                              const float* __restrict__ kb,
                                              float* __restrict__ sw, int sc) {
    int sl   = blockIdx.x;
    int s    = sc * 256 + sl;
    int w    = threadIdx.x >> 6;
    int lane = threadIdx.x & 63;
    float gv = kg[lane], bv = kb[lane];
    float acc0 = 0.f, acc1 = 0.f;
    for (int n = w; n < 384; n += 4) {
        const float* row = kraw + ((size_t)sl * 384 + n) * 128;
        #pragma unroll
        for (int tt = 0; tt < 2; ++tt) {
            float v = row[tt * 64 + lane];
            float sum = v;
            #pragma unroll
            for (int m = 1; m < 64; m <<= 1) sum += __shfl_xor(sum, m);
            float mean = sum * (1.0f / 64.0f);
            float dv = v - mean;
            float sq = dv * dv;
            #pragma unroll
            for (int m = 1; m < 64; m <<= 1) sq += __shfl_xor(sq, m);
            float r  = rsqrtf(sq * (1.0f / 64.0f) + 1e-5f);
            float kn = dv * r * gv + bv;
            float p  = kn * qn[(size_t)(tt * 384 + n) * 64 + lane];
            #pragma unroll
            for (int m = 1; m < 64; m <<= 1) p += __shfl_xor(p, m);
            if (tt == 0) acc0 += p; else acc1 += p;
        }
    }
    __shared__ float red[8];
    if (lane == 0) { red[w] = acc0; red[4 + w] = acc1; }
    __syncthreads();
    if (threadIdx.x == 0) {
        float t0 = red[0] + red[1] + red[2] + red[3];
        float t1 = red[4] + red[5] + red[6] + red[7];
        sw[s]       = t0 * 0.125f / 384.0f;
        sw[512 + s] = t1 * 0.125f / 384.0f;
    }
}

// ---------------- K4: lambda, softmax over s, sqrt weights ----------------
__global__ __launch_bounds__(512) void k4_softmax(const float* __restrict__ sw,
                                                  const float* __restrict__ lq1,
                                                  const float* __restrict__ lk1,
                                                  const float* __restrict__ lq2,
                                                  const float* __restrict__ lk2,
                                                  float* __restrict__ wsq) {
    int s = threadIdx.x;
    float l1 = 0.f, l2 = 0.f;
    for (int i = 0; i < 64; ++i) { l1 += lq1[i] * lk1[i]; l2 += lq2[i] * lk2[i]; }
    float lam = expf(l1) - expf(l2) + 1.0f;
    float v = sw[s] - lam * sw[512 + s];
    __shared__ float red[512];
    red[s] = v;
    __syncthreads();
    for (int off = 256; off > 0; off >>= 1) {
        if (s < off) red[s] = fmaxf(red[s], red[s + off]);
        __syncthreads();
    }
    float mx = red[0];
    __syncthreads();
    float e = expf(v - mx);
    red[s] = e;
    __syncthreads();
    for (int off = 256; off > 0; off >>= 1) {
        if (s < off) red[s] += red[s + off];
        __syncthreads();
    }
    wsq[s] = sqrtf(e / red[0] + 1e-32f);
}

// ---------------- K5: build Aext/Bext (hi/lo bf16 split, K-sections) ----------------
__global__ __launch_bounds__(256) void k5_ab(const float* __restrict__ x,
                                             const float* __restrict__ Wl,
                                             const float* __restrict__ Wr,
                                             const float* __restrict__ wsq,
                                             unsigned short* __restrict__ Aext,
                                             unsigned short* __restrict__ Bext) {
    int i  = blockIdx.x;
    int s0 = blockIdx.y * 64;
    int t  = threadIdx.x;
    __shared__ __align__(16) float wl[2048], wr[2048];
    __shared__ float xT[64][69];
    ((float4*)wl)[t * 2]     = ((const float4*)Wl)[t * 2];
    ((float4*)wl)[t * 2 + 1] = ((const float4*)Wl)[t * 2 + 1];
    ((float4*)wr)[t * 2]     = ((const float4*)Wr)[t * 2];
    ((float4*)wr)[t * 2 + 1] = ((const float4*)Wr)[t * 2 + 1];
    {
        int s_l = t >> 2, d0 = (t & 3) * 16;
        const float* xr = x + ((size_t)(s0 + s_l) * 384 + i) * 64 + d0;
        #pragma unroll
        for (int j = 0; j < 4; ++j) {
            float4 v = *(const float4*)(xr + j * 4);
            xT[d0 + j * 4 + 0][s_l] = v.x; xT[d0 + j * 4 + 1][s_l] = v.y;
            xT[d0 + j * 4 + 2][s_l] = v.z; xT[d0 + j * 4 + 3][s_l] = v.w;
        }
    }
    __syncthreads();
    int c = t >> 3, so = (t & 7) * 8;
    float aa[8] = {}, bb2[8] = {};
    #pragma unroll 8
    for (int d = 0; d < 64; ++d) {
        float wlv = wl[c * 64 + d], wrv = wr[c * 64 + d];
        #pragma unroll
        for (int q = 0; q < 8; ++q) {
            float xv = xT[d][so + q];
            aa[q]  += xv * wlv;
            bb2[q] += xv * wrv;
        }
    }
    #pragma unroll
    for (int q = 0; q < 8; ++q) {
        float wq = wsq[s0 + so + q];
        aa[q] *= wq; bb2[q] *= wq;
    }
    size_t row = (size_t)i * 32 + c;
    {
        unsigned short h[8]; unsigned short l[8];
        #pragma unroll
        for (int q = 0; q < 8; ++q) { h[q] = f2b(aa[q]); l[q] = f2b(aa[q] - b2f(h[q])); }
        uint4 H = make_uint4((unsigned)h[0] | ((unsigned)h[1] << 16), (unsigned)h[2] | ((unsigned)h[3] << 16),
                             (unsigned)h[4] | ((unsigned)h[5] << 16), (unsigned)h[6] | ((unsigned)h[7] << 16));
        uint4 L = make_uint4((unsigned)l[0] | ((unsigned)l[1] << 16), (unsigned)l[2] | ((unsigned)l[3] << 16),
                             (unsigned)l[4] | ((unsigned)l[5] << 16), (unsigned)l[6] | ((unsigned)l[7] << 16));
        *(uint4*)&Aext[row * 1024 + s0 + so]       = H;
        *(uint4*)&Aext[row * 1024 + 512 + s0 + so] = L;
    }
    {
        unsigned short h[8]; unsigned short l[8];
        #pragma unroll
        for (int q = 0; q < 8; ++q) { h[q] = f2b(bb2[q]); l[q] = f2b(bb2[q] - b2f(h[q])); }
        uint4 H = make_uint4((unsigned)h[0] | ((unsigned)h[1] << 16), (unsigned)h[2] | ((unsigned)h[3] << 16),
                             (unsigned)h[4] | ((unsigned)h[5] << 16), (unsigned)h[6] | ((unsigned)h[7] << 16));
        uint4 L = make_uint4((unsigned)l[0] | ((unsigned)l[1] << 16), (unsigned)l[2] | ((unsigned)l[3] << 16),
                             (unsigned)l[4] | ((unsigned)l[5] << 16), (unsigned)l[6] | ((unsigned)l[7] << 16));
        *(uint4*)&Bext[row * 1024 + s0 + so]       = H;
        *(uint4*)&Bext[row * 1024 + 512 + s0 + so] = L;
    }
}

// ---------------- prep: WpF frag layout [bsel][nb][kstep][lane][8] + bpP ----------------
// logical u-row r: r even -> Wp row r/2 (val), r odd -> Wp row 128+r/2 (gate).
// Frag (nb,kstep): lane l holds rows nb*16+(l&15), k = kstep*32+(l>>4)*8 .. +7.
// bsel 0 = hi(bf16(w)), bsel 1 = lo(bf16(w - hi)).
__global__ __launch_bounds__(256) void prep_wp(const float* __restrict__ Wp,
                                               const float* __restrict__ bp,
                                               unsigned short* __restrict__ WpF,
                                               float* __restrict__ bpP) {
    int gid = blockIdx.x * 256 + threadIdx.x;      // 256 blocks -> 65536 groups
    int lane  = gid & 63;
    int kstep = (gid >> 6) & 31;
    int nb    = (gid >> 11) & 15;
    int bsel  = gid >> 15;
    int rl = lane & 15, kg = lane >> 4;
    int urow = nb * 16 + rl;
    int srow = (urow & 1) ? 128 + (urow >> 1) : (urow >> 1);
    int k0 = kstep * 32 + kg * 8;
    const float* src = Wp + (size_t)srow * 1024 + k0;
    unsigned short o[8];
    #pragma unroll
    for (int e = 0; e < 8; ++e) {
        float w = src[e];
        unsigned short h = f2b(w);
        o[e] = bsel ? f2b(w - b2f(h)) : h;
    }
    *(uint4*)&WpF[(size_t)gid * 8] = make_uint4(
        (unsigned)o[0] | ((unsigned)o[1] << 16), (unsigned)o[2] | ((unsigned)o[3] << 16),
        (unsigned)o[4] | ((unsigned)o[5] << 16), (unsigned)o[6] | ((unsigned)o[7] << 16));
    if (blockIdx.x == 0) {
        int tt = threadIdx.x;
        bpP[tt] = bp[(tt & 1) ? 128 + (tt >> 1) : (tt >> 1)];
    }
}

// ---------------- FUSED: outer-product tile (bf16x3 MFMA) + Wp projection + SwiGLU ----------------
// grid (96,96): 128x128 outer tile = 16 (i,j) pairs, each fully projected in-block.
__global__ __launch_bounds__(256) void gemm_fused(const unsigned short* __restrict__ A,
                                                  const unsigned short* __restrict__ B,
                                                  const unsigned short* __restrict__ WpF,
                                                  const float* __restrict__ bpP,
                                                  float* __restrict__ out) {
    __shared__ __align__(16) unsigned char smem[65536];
    unsigned short* As = (unsigned short*)smem;            // [128*32] = 8 KB
    unsigned short* Bs = (unsigned short*)(smem + 8192);   // [128*32] = 8 KB
    unsigned*       pa = (unsigned*)smem;                  // [16][1024] packed hi|lo, 64 KB (aliases As/Bs)

    const int t = threadIdx.x;
    const int wave = t >> 6, lane = t & 63;
    const int m0 = blockIdx.x * 128, n0 = blockIdx.y * 128;
    const int wm = (wave & 1) * 64, wn = (wave >> 1) * 64;
    const int kgrp = lane >> 4, rl = lane & 15;
    const int rb0 = kgrp * 4;
    f32x4 acc[4][4] = {};

    // ---- main loop: outer tile, bf16x3 over ext-K 1536 ----
    for (int kk0 = 0; kk0 < 1536; kk0 += 32) {
        const int sec = kk0 >> 9;
        const int kl  = kk0 & 511;
        const int scolA = (sec == 1) ? 512 + kl : kl;
        const int scolB = (sec == 2) ? 512 + kl : kl;
        #pragma unroll
        for (int is = 0; is < 2; ++is) {
            const int u   = wave * 128 + is * 64 + lane;
            const int row = u >> 2;
            const int blk = (u & 3) ^ ((u >> 3) & 3);
            GLDS(A + (size_t)(m0 + row) * 1024 + scolA + blk * 8, As + (size_t)(wave * 128 + is * 64) * 8);
            GLDS(B + (size_t)(n0 + row) * 1024 + scolB + blk * 8, Bs + (size_t)(wave * 128 + is * 64) * 8);
        }
        __syncthreads();
        bf16x8 aF[4], bF[4];
        #pragma unroll
        for (int f = 0; f < 4; ++f) {
            int ra = wm + f * 16 + rl;
            aF[f] = *(const bf16x8*)&As[ra * 32 + (kgrp ^ ((ra >> 1) & 3)) * 8];
            int rb = wn + f * 16 + rl;
            bF[f] = *(const bf16x8*)&Bs[rb * 32 + (kgrp ^ ((rb >> 1) & 3)) * 8];
        }
        #pragma unroll
        for (int mf = 0; mf < 4; ++mf)
            #pragma unroll
            for (int nf = 0; nf < 4; ++nf)
                acc[mf][nf] = __builtin_amdgcn_mfma_f32_16x16x32_bf16(aF[mf], bF[nf], acc[mf][nf], 0, 0, 0);
        __syncthreads();
    }

    // ---- spill outer tile to pa as packed hi|lo bf16 (pair-major, swizzled) ----
    // safe: all As/Bs reads completed before the loop's final barrier.
    #pragma unroll
    for (int mf = 0; mf < 4; ++mf) {
        #pragma unroll
        for (int nf = 0; nf < 4; ++nf) {
            #pragma unroll
            for (int r = 0; r < 4; ++r) {
                int mloc = wm + mf * 16 + rb0 + r;
                int nloc = wn + nf * 16 + rl;
                int p = ((mloc >> 5) << 2) | (nloc >> 5);
                int k = ((mloc & 31) << 5) | (nloc & 31);
                float v = acc[mf][nf][r];
                unsigned short h = f2b(v);
                unsigned short l = f2b(v - b2f(h));
                pa[(p << 10) + (k ^ ((p & 3) << 3))] = (unsigned)h | ((unsigned)l << 16);
            }
        }
    }
    __syncthreads();

    // ---- epilogue GEMM: [16 pairs] x WpF^T (K=1024, 3 bf16 sections) ----
    f32x4 acc2[4] = {};
    const int kg8 = kgrp * 8;
    // pass 0: B = WH, A = hi AND lo (sections 0,1 share B)
    #pragma unroll 2
    for (int ks = 0; ks < 32; ++ks) {
        U4B8 ua0, ua1, aH, aL;
        int kb = (ks * 32 + kg8) ^ ((rl & 3) << 3);
        ua0.u4 = *(const uint4*)&pa[(rl << 10) + kb];
        ua1.u4 = *(const uint4*)&pa[(rl << 10) + kb + 4];
        aH.u[0] = (ua0.u[0] & 0xffffu) | (ua0.u[1] << 16);
        aH.u[1] = (ua0.u[2] & 0xffffu) | (ua0.u[3] << 16);
        aH.u[2] = (ua1.u[0] & 0xffffu) | (ua1.u[1] << 16);
        aH.u[3] = (ua1.u[2] & 0xffffu) | (ua1.u[3] << 16);
        aL.u[0] = (ua0.u[0] >> 16) | (ua0.u[1] & 0xffff0000u);
        aL.u[1] = (ua0.u[2] >> 16) | (ua0.u[3] & 0xffff0000u);
        aL.u[2] = (ua1.u[0] >> 16) | (ua1.u[1] & 0xffff0000u);
        aL.u[3] = (ua1.u[2] >> 16) | (ua1.u[3] & 0xffff0000u);
        bf16x8 bF[4];
        #pragma unroll
        for (int nf = 0; nf < 4; ++nf)
            bF[nf] = *(const bf16x8*)&WpF[(size_t)((((wave * 4 + nf) * 32) + ks) * 64 + lane) * 8];
        #pragma unroll
        for (int nf = 0; nf < 4; ++nf)
            acc2[nf] = __builtin_amdgcn_mfma_f32_16x16x32_bf16(aH.v, bF[nf], acc2[nf], 0, 0, 0);
        #pragma unroll
        for (int nf = 0; nf < 4; ++nf)
            acc2[nf] = __builtin_amdgcn_mfma_f32_16x16x32_bf16(aL.v, bF[nf], acc2[nf], 0, 0, 0);
    }
    // pass 1: B = WL, A = hi
    #pragma unroll 2
    for (int ks = 0; ks < 32; ++ks) {
        U4B8 ua0, ua1, aH;
        int kb = (ks * 32 + kg8) ^ ((rl & 3) << 3);
        ua0.u4 = *(const uint4*)&pa[(rl << 10) + kb];
        ua1.u4 = *(const uint4*)&pa[(rl << 10) + kb + 4];
        aH.u[0] = (ua0.u[0] & 0xffffu) | (ua0.u[1] << 16);
        aH.u[1] = (ua0.u[2] & 0xffffu) | (ua0.u[3] << 16);
        aH.u[2] = (ua1.u[0] & 0xffffu) | (ua1.u[1] << 16);
        aH.u[3] = (ua1.u[2] & 0xffffu) | (ua1.u[3] << 16);
        bf16x8 bF[4];
        #pragma unroll
        for (int nf = 0; nf < 4; ++nf)
            bF[nf] = *(const bf16x8*)&WpF[(size_t)(((16 * 32 + (wave * 4 + nf) * 32) + ks) * 64 + lane) * 8];
        #pragma unroll
        for (int nf = 0; nf < 4; ++nf)
            acc2[nf] = __builtin_amdgcn_mfma_f32_16x16x32_bf16(aH.v, bF[nf], acc2[nf], 0, 0, 0);
    }

    // ---- bias + SwiGLU + store ----
    const int parity = rl & 1;
    #pragma unroll
    for (int nf = 0; nf < 4; ++nf) {
        const int np = wave * 64 + nf * 16 + rl;   // logical u-row (interleaved val/gate)
        const float bias = bpP[np];
        const int ocol = np >> 1;
        #pragma unroll
        for (int r = 0; r < 4; ++r) {
            float own = acc2[nf][r] + bias;
            float oth = __shfl_xor(own, 1);
            float v = parity ? oth : own;
            float g = parity ? own : oth;
            float res = v * (g / (1.0f + expf(-g)));
            if (parity == (r >> 1)) {
                int p = rb0 + r;                    // pair index = C row
                int i = blockIdx.x * 4 + (p >> 2);
                int j = blockIdx.y * 4 + (p & 3);
                out[((size_t)i * 384 + j) * 128 + ocol] = res;
            }
        }
    }
}

extern "C" void kernel_launch(void* const* d_in, const int* in_sizes, int n_in,
                              void* d_out, int out_size, void* d_ws, size_t ws_size,
                              hipStream_t stream) {
    const float* msa  = (const float*)d_in[0];
    const float* ln_g = (const float*)d_in[1];
    const float* ln_b = (const float*)d_in[2];
    const float* Wq   = (const float*)d_in[3];
    const float* Wk   = (const float*)d_in[4];
    const float* qn_g = (const float*)d_in[5];
    const float* qn_b = (const float*)d_in[6];
    const float* kn_g = (const float*)d_in[7];
    const float* kn_b = (const float*)d_in[8];
    const float* lq1  = (const float*)d_in[9];
    const float* lk1  = (const float*)d_in[10];
    const float* lq2  = (const float*)d_in[11];
    const float* lk2  = (const float*)d_in[12];
    const float* Wl   = (const float*)d_in[13];
    const float* Wr   = (const float*)d_in[14];
    const float* Wp   = (const float*)d_in[15];
    const float* bp   = (const float*)d_in[16];
    float* out = (float*)d_out;
    float* ws  = (float*)d_ws;

    float* x = ws + WS_X;
    unsigned short* AextS = (unsigned short*)(ws + WS_AEXT);
    unsigned short* BextS = (unsigned short*)(ws + WS_BEXT);
    float* qn  = ws + WS_QN;
    float* sw  = ws + WS_SW;
    float* wsq = ws + WS_WSQ;
    float* bpP = ws + WS_BPP;
    unsigned short* WpF = (unsigned short*)(ws + WS_WPF);
    float* kraw = ws + WS_BIG;

    prep_wp<<<256, 256, 0, stream>>>(Wp, bp, WpF, bpP);
    k1_ln<<<49152, 256, 0, stream>>>(msa, ln_g, ln_b, x);
    k2_q<<<384, 128, 0, stream>>>(x, Wq, qn_g, qn_b, qn);
    for (int sc = 0; sc < 2; ++sc) {
        gemm_nt<<<dim3(768, 1), 256, 0, stream>>>(x + (size_t)sc * 98304 * 64, Wk, kraw, 64, 64, 64, 128);
        k3b_sw<<<256, 256, 0, stream>>>(kraw, qn, kn_g, kn_b, sw, sc);
    }
    k4_softmax<<<1, 512, 0, stream>>>(sw, lq1, lk1, lq2, lk2, wsq);
    k5_ab<<<dim3(384, 8), 256, 0, stream>>>(x, Wl, Wr, wsq, AextS, BextS);
    gemm_fused<<<dim3(96, 96), 256, 0, stream>>>(AextS, BextS, WpF, bpP, out);
}